// Round 1
// 369.085 us; speedup vs baseline: 1.3848x; 1.3848x over previous
//
#include <hip/hip_runtime.h>
#include <hip/hip_bf16.h>

typedef __hip_bfloat16 bf16;
typedef __attribute__((ext_vector_type(8))) __bf16 bf16x8;
typedef __attribute__((ext_vector_type(4))) float f32x4;

#define MFMA16(a, b, c) __builtin_amdgcn_mfma_f32_16x16x32_bf16((a), (b), (c), 0, 0, 0)

#define BT 4096      // B*T rows
#define CE 2048      // embed dim
#define NQKV 3072    // q(2048) + k(512) + v(512)
#define TSEQ 2048
#define HD 128

// q pre-scale: 1/sqrt(128) * log2(e), folded into rope_rms's q output.
#define QSCALE (0.08838834764831845f * 1.4426950408889634f)
// fixed softmax max bound: ||q'||*||k|| = 128*QSCALE (Cauchy-Schwarz on
// RMS-normalized vectors). p = 2^(s' - M2) <= ~1, no online max needed.
#define M2 16.3222f

// ---------------------------------------------------------------------------
// async global->LDS 16B copy (one instruction, no VGPR round trip)
__device__ __forceinline__ void gld16(const void* g, void* l)
{
    __builtin_amdgcn_global_load_lds(
        (const __attribute__((address_space(1))) void*)g,
        (__attribute__((address_space(3))) void*)l, 16, 0, 0);
}

// ---------------------------------------------------------------------------
// Input-dtype detector (R4-confirmed: inputs are fp32; gate kept for safety).
__global__ void detect_dtype(const unsigned short* __restrict__ x, int* __restrict__ flag)
{
    __shared__ int cnt;
    if (threadIdx.x == 0) cnt = 0;
    __syncthreads();
    unsigned short w = x[2 * threadIdx.x];
    int e = (w >> 7) & 0xFF;
    atomicAdd(&cnt, (e >= 117 && e <= 130) ? 1 : 0);
    __syncthreads();
    if (threadIdx.x == 0) *flag = (cnt < 128) ? 1 : 0;
}

// Stage 8 elems (16B bf16) into LDS from bf16 or fp32 source (VGPR convert).
__device__ __forceinline__ void stage8(short* dst, const void* src, size_t eoff, bool f32)
{
    if (f32) {
        const float* s = (const float*)src + eoff;
        float4 f0 = *(const float4*)s;
        float4 f1 = *(const float4*)(s + 4);
        bf16x8 v;
        v[0] = (__bf16)f0.x; v[1] = (__bf16)f0.y; v[2] = (__bf16)f0.z; v[3] = (__bf16)f0.w;
        v[4] = (__bf16)f1.x; v[5] = (__bf16)f1.y; v[6] = (__bf16)f1.z; v[7] = (__bf16)f1.w;
        *(bf16x8*)dst = v;
    } else {
        *(uint4*)dst = *(const uint4*)((const bf16*)src + eoff);
    }
}

__device__ __forceinline__ float ldf(const void* p, int i, bool f32)
{
    return f32 ? ((const float*)p)[i] : __bfloat162float(((const bf16*)p)[i]);
}

// ---------------------------------------------------------------------------
// fp32 (or bf16) -> bf16 conversion, 8 elems/thread.
__global__ __launch_bounds__(256)
void conv_bf16(const void* __restrict__ src, bf16* __restrict__ dst,
               const int* __restrict__ flagp)
{
    const bool f = *flagp != 0;
    size_t i8 = (size_t)blockIdx.x * 256 + threadIdx.x;
    stage8((short*)(dst + i8 * 8), src, i8 * 8, f);
}

// ---------------------------------------------------------------------------
// C[M,N] = A[M,K] @ W[N,K]^T, fp32 accum. (unchanged)
__global__ __launch_bounds__(256)
void gemm_bt(const void* __restrict__ A, const bf16* __restrict__ W,
             void* __restrict__ C, int M, int N, int K, int lda,
             int aGate, int oGate, const int* __restrict__ flagp)
{
    __shared__ short As[128][32];
    __shared__ short Bs[128][32];

    const int f = *flagp;
    const bool aF = aGate && f, oF = oGate && f;

    const int tid   = threadIdx.x;
    const int lane  = tid & 63;
    const int wid   = tid >> 6;
    const int row16 = lane & 15;
    const int quad  = lane >> 4;
    const int wr    = wid >> 1;
    const int wc    = wid & 1;
    const int m0    = blockIdx.y * 128;
    const int n0    = blockIdx.x * 128;

    const int rl4 = wid * 16 + (lane >> 2);
    const int c8  = (lane & 3) * 8;

    f32x4 acc[4][4];
#pragma unroll
    for (int i = 0; i < 4; i++)
#pragma unroll
        for (int j = 0; j < 4; j++)
            acc[i][j] = (f32x4){0.f, 0.f, 0.f, 0.f};

    for (int k0 = 0; k0 < K; k0 += 32) {
#pragma unroll
        for (int i = 0; i < 2; i++) {
            int r = i * 64 + rl4;
            gld16(W + (size_t)(n0 + r) * K + k0 + c8, &Bs[r][c8]);
        }
        if (!aF) {
#pragma unroll
            for (int i = 0; i < 2; i++) {
                int r = i * 64 + rl4;
                gld16((const bf16*)A + (size_t)(m0 + r) * lda + k0 + c8, &As[r][c8]);
            }
        } else {
#pragma unroll
            for (int i = 0; i < 2; i++) {
                int c = i * 256 + tid;
                int row = c >> 2, col = (c & 3) << 3;
                stage8(&As[row][col], A, (size_t)(m0 + row) * lda + k0 + col, true);
            }
        }
        __syncthreads();

        bf16x8 af[4], bfv[4];
#pragma unroll
        for (int mi = 0; mi < 4; mi++)
            af[mi] = *(const bf16x8*)&As[wr * 64 + mi * 16 + row16][quad * 8];
#pragma unroll
        for (int ni = 0; ni < 4; ni++)
            bfv[ni] = *(const bf16x8*)&Bs[wc * 64 + ni * 16 + row16][quad * 8];
#pragma unroll
        for (int mi = 0; mi < 4; mi++)
#pragma unroll
            for (int ni = 0; ni < 4; ni++)
                acc[mi][ni] = MFMA16(af[mi], bfv[ni], acc[mi][ni]);
        __syncthreads();
    }

#pragma unroll
    for (int mi = 0; mi < 4; mi++) {
        int rowb = m0 + wr * 64 + mi * 16 + quad * 4;
#pragma unroll
        for (int ni = 0; ni < 4; ni++) {
            int col = n0 + wc * 64 + ni * 16 + row16;
#pragma unroll
            for (int r = 0; r < 4; r++) {
                size_t idx = (size_t)(rowb + r) * N + col;
                float  v   = acc[mi][ni][r];
                if (oF) ((float*)C)[idx] = v;
                else    ((bf16*)C)[idx]  = __float2bfloat16(v);
            }
        }
    }
}

// ---------------------------------------------------------------------------
// RoPE + RMSNorm in place in qkv; q additionally scaled by QSCALE. (unchanged)
__global__ __launch_bounds__(256)
void rope_rms(bf16* __restrict__ qkv, const void* __restrict__ cosp,
              const void* __restrict__ sinp, const int* __restrict__ flagp)
{
    const bool f = *flagp != 0;
    const int wg   = blockIdx.x * 4 + (threadIdx.x >> 6);
    const int lane = threadIdx.x & 63;
    const int s    = wg % 20;
    const int m    = wg / 20;
    const int t    = m & (TSEQ - 1);

    const int col = (s < 16) ? s * HD : CE + (s - 16) * HD;
    bf16* p = qkv + (size_t)m * NQKV + col;

    float xlo = __bfloat162float(p[lane]);
    float xhi = __bfloat162float(p[lane + 64]);
    float cl  = ldf(cosp, t * HD + lane, f);
    float sl  = ldf(sinp, t * HD + lane, f);
    float ch  = ldf(cosp, t * HD + 64 + lane, f);
    float sh  = ldf(sinp, t * HD + 64 + lane, f);

    float rlo = xlo * cl - xhi * sl;
    float rhi = xhi * ch + xlo * sh;

    float ss = rlo * rlo + rhi * rhi;
#pragma unroll
    for (int off = 32; off > 0; off >>= 1)
        ss += __shfl_xor(ss, off, 64);
    float inv = rsqrtf(ss * (1.0f / 128.0f) + 1.1920929e-07f);
    if (s < 16) inv *= QSCALE;

    p[lane]      = __float2bfloat16(rlo * inv);
    p[lane + 64] = __float2bfloat16(rhi * inv);
}

// ---------------------------------------------------------------------------
// vt[b, hk, d, t] = qkv[(b*T+t)*3072 + 2560 + hk*128 + d]  (unchanged)
__global__ __launch_bounds__(256)
void vtrans(const bf16* __restrict__ qkv, bf16* __restrict__ vt)
{
    int idx = blockIdx.x * 256 + threadIdx.x;
    int t  = idx & (TSEQ - 1);
    int d  = (idx >> 11) & 127;
    int bh = idx >> 18;
    vt[idx] = qkv[((size_t)((bh >> 2) * TSEQ + t)) * NQKV + 2560 + (bh & 3) * HD + d];
}

// ---------------------------------------------------------------------------
// Flash attention R9: GQA-fused + double-buffered.
//   block = (b, hk, 64-row q-tile): 512 thr / 8 waves = 4 heads x 2 row-halves.
//   K/V staged ONCE per tile for all 4 heads (4x better MFMA:stage ratio, 4x
//   less L2 traffic vs R8), via global_load_lds into LINEAR LDS whose image is
//   XOR-chunk-swizzled (pre-swizzled global source, m173): phys = c ^ (row&7)
//   at 16B granularity -> ds_read_b128 fragment reads hit the 8-cycle minimum
//   (unswizzled [.][128]/[.][64] bf16 rows alias banks).
//   2-phase pipeline: issue next tile's gld16 BEFORE computing current tile;
//   one __syncthreads per tile (its implicit vmcnt(0) drains the stage).
//   LDS 100KB -> 1 block/CU, 8 waves. Grid 256 blocks = all CUs resident.
//   Softmax math unchanged (fixed-max exp2, O in place into qkv's Q columns).
__global__ __launch_bounds__(512, 2)
void attn(bf16* __restrict__ qkv, const bf16* __restrict__ vt)
{
    __shared__ __bf16 Ks[2][64][128];    // swizzled image, 2x16KB
    __shared__ __bf16 Vs[2][128][64];    // swizzled image, 2x16KB
    __shared__ __bf16 Pl[8][2][16][72];  // per-wave P transpose, 36.9KB

    const int tid   = threadIdx.x;
    const int lane  = tid & 63;
    const int wid   = tid >> 6;
    const int row16 = lane & 15;
    const int quad  = lane >> 4;
    const int b   = blockIdx.y >> 2;
    const int hk  = blockIdx.y & 3;
    const int h   = hk * 4 + (wid & 3);   // wave's q-head
    const int mh  = wid >> 2;             // wave's 32-row half
    const int xi  = blockIdx.x;
    const int q0  = xi * 64;
    const int qr0 = q0 + mh * 32;

    const bf16* Q  = qkv + ((size_t)(b * TSEQ + qr0)) * NQKV + h * HD;
    const bf16* Kp = qkv + ((size_t)(b * TSEQ)) * NQKV + CE + hk * HD;
    const bf16* Vp = vt + ((size_t)(b * 4 + hk) * HD) * TSEQ;

    char* const KsB = (char*)Ks;
    char* const VsB = (char*)Vs;

    // staging: wave w owns K rows [8w,8w+8) and V rows [16w,16w+16).
    // gld16 dest = wave-uniform base + lane*16 (linear); the swizzle lives in
    // the per-lane GLOBAL address: logical chunk c = phys ^ (row&7).
    auto stage = [&](int buf, int k0) {
#pragma unroll
        for (int i = 0; i < 2; i++) {
            int kr = (wid << 3) + i * 4 + (lane >> 4);
            int kc = (lane & 15) ^ (kr & 7);
            gld16(Kp + (size_t)(k0 + kr) * NQKV + kc * 8,
                  KsB + buf * 16384 + ((wid << 3) + i * 4) * 256 + lane * 16);
            int vr = (wid << 4) + i * 8 + (lane >> 3);
            int vc = (lane & 7) ^ (vr & 7);
            gld16(Vp + (size_t)vr * TSEQ + k0 + vc * 8,
                  VsB + buf * 16384 + ((wid << 4) + i * 8) * 128 + lane * 16);
        }
    };

    // Q fragments: 2 mfrags x 128-d (4 k-slices)
    bf16x8 aq[2][4];
#pragma unroll
    for (int mi = 0; mi < 2; mi++)
#pragma unroll
        for (int ds = 0; ds < 4; ds++)
            aq[mi][ds] = *(const bf16x8*)(Q + (size_t)(mi * 16 + row16) * NQKV
                                          + ds * 32 + quad * 8);

    f32x4 o[2][8];
#pragma unroll
    for (int mi = 0; mi < 2; mi++)
#pragma unroll
        for (int dt = 0; dt < 8; dt++)
            o[mi][dt] = (f32x4){0.f, 0.f, 0.f, 0.f};
    float lsum[2][4] = {{0.f, 0.f, 0.f, 0.f}, {0.f, 0.f, 0.f, 0.f}};

    stage(0, 0);
    __syncthreads();

    for (int t = 0; t <= xi; t++) {
        const int cur = t & 1;
        if (t < xi) stage(cur ^ 1, (t + 1) * 64);   // prefetch under compute

        // QK^T: K frag read once, feeds both mfrags
        f32x4 s[2][4];
#pragma unroll
        for (int mi = 0; mi < 2; mi++)
#pragma unroll
            for (int kg = 0; kg < 4; kg++)
                s[mi][kg] = (f32x4){0.f, 0.f, 0.f, 0.f};

        __builtin_amdgcn_s_setprio(1);
#pragma unroll
        for (int ds = 0; ds < 4; ds++) {
#pragma unroll
            for (int kg = 0; kg < 4; kg++) {
                int krow = kg * 16 + row16;
                int phys = (ds * 4 + quad) ^ (row16 & 7);
                bf16x8 kf = *(const bf16x8*)(KsB + cur * 16384 + krow * 256 + phys * 16);
                s[0][kg] = MFMA16(aq[0][ds], kf, s[0][kg]);
                s[1][kg] = MFMA16(aq[1][ds], kf, s[1][kg]);
            }
        }
        __builtin_amdgcn_s_setprio(0);

        // fixed-max softmax numerators; per-lane partial sums; P -> LDS
        const bool diag = (t == xi);
        const int  k0   = t * 64;
#pragma unroll
        for (int mi = 0; mi < 2; mi++) {
#pragma unroll
            for (int r = 0; r < 4; r++) {
                float p[4];
                int qrow = qr0 + mi * 16 + quad * 4 + r;
#pragma unroll
                for (int kg = 0; kg < 4; kg++) {
                    float e = __builtin_amdgcn_exp2f(s[mi][kg][r] - M2);
                    p[kg] = (!diag || (k0 + kg * 16 + row16 <= qrow)) ? e : 0.f;
                }
                lsum[mi][r] += (p[0] + p[1]) + (p[2] + p[3]);
#pragma unroll
                for (int kg = 0; kg < 4; kg++)
                    Pl[wid][mi][quad * 4 + r][kg * 16 + row16] = (__bf16)p[kg];
            }
        }
        __asm__ volatile("" ::: "memory");

        // PV: V frag read once, feeds both mfrags
        __builtin_amdgcn_s_setprio(1);
#pragma unroll
        for (int c = 0; c < 2; c++) {
            bf16x8 pf0 = *(const bf16x8*)&Pl[wid][0][row16][c * 32 + quad * 8];
            bf16x8 pf1 = *(const bf16x8*)&Pl[wid][1][row16][c * 32 + quad * 8];
#pragma unroll
            for (int dt = 0; dt < 8; dt++) {
                int vrow = dt * 16 + row16;
                int phys = (c * 4 + quad) ^ (row16 & 7);
                bf16x8 vf = *(const bf16x8*)(VsB + cur * 16384 + vrow * 128 + phys * 16);
                o[0][dt] = MFMA16(pf0, vf, o[0][dt]);
                o[1][dt] = MFMA16(pf1, vf, o[1][dt]);
            }
        }
        __builtin_amdgcn_s_setprio(0);
        __asm__ volatile("" ::: "memory");
        __syncthreads();   // all reads of `cur` done; stage(t+1) landed
    }

    // final 16-lane reduction of l per row; write O into qkv's Q slot
#pragma unroll
    for (int mi = 0; mi < 2; mi++) {
#pragma unroll
        for (int r = 0; r < 4; r++) {
            float l = lsum[mi][r];
#pragma unroll
            for (int off = 1; off < 16; off <<= 1)
                l += __shfl_xor(l, off, 64);
            float rl = 1.0f / l;
            int trow = qr0 + mi * 16 + quad * 4 + r;
            bf16* dst = qkv + ((size_t)(b * TSEQ + trow)) * NQKV + h * HD;
#pragma unroll
            for (int dt = 0; dt < 8; dt++)
                dst[dt * 16 + row16] = __float2bfloat16(o[mi][dt][r] * rl);
        }
    }
}

// ---------------------------------------------------------------------------
extern "C" void kernel_launch(void* const* d_in, const int* in_sizes, int n_in,
                              void* d_out, int out_size, void* d_ws, size_t ws_size,
                              hipStream_t stream)
{
    // ws (bf16 elems): qkv [4096,3072] 25.2MB | vt 4.2MB | wqkvb [3072,2048]
    // 12.6MB (reused for wprojb after gemm1) | flag. ~42MB.
    bf16* qkv   = (bf16*)d_ws;
    bf16* vt    = qkv + (size_t)BT * NQKV;
    bf16* wqkvb = vt + (size_t)2 * 4 * HD * TSEQ;
    int* flagp  = (int*)(wqkvb + (size_t)NQKV * CE);

    // 0) detect input dtype -> device flag
    detect_dtype<<<1, 256, 0, stream>>>((const unsigned short*)d_in[0], flagp);

    // 1) convert wq/wk/wv to fused bf16 [3072][2048]
    conv_bf16<<<(2048 * 2048 / 8) / 256, 256, 0, stream>>>(d_in[3], wqkvb, flagp);
    conv_bf16<<<(512 * 2048 / 8) / 256, 256, 0, stream>>>(d_in[4], wqkvb + (size_t)2048 * 2048, flagp);
    conv_bf16<<<(512 * 2048 / 8) / 256, 256, 0, stream>>>(d_in[5], wqkvb + (size_t)2560 * 2048, flagp);

    // 2) fused QKV projection
    gemm_bt<<<dim3(NQKV / 128, BT / 128), 256, 0, stream>>>(
        d_in[0], wqkvb, qkv, BT, NQKV, CE, CE, 1, 0, flagp);

    // 3) convert wproj into the same buffer (stream-ordered after gemm1)
    conv_bf16<<<(2048 * 2048 / 8) / 256, 256, 0, stream>>>(d_in[6], wqkvb, flagp);

    // 4) V transpose to [B,KV,D,T]
    vtrans<<<(2 * 4 * HD * TSEQ) / 256, 256, 0, stream>>>(qkv, vt);

    // 5) RoPE + RMSNorm in place (q scaled by QSCALE)
    rope_rms<<<(BT * 20) / 4, 256, 0, stream>>>(qkv, d_in[1], d_in[2], flagp);

    // 6) GQA-fused flash attention; O overwrites qkv's Q columns
    attn<<<dim3(TSEQ / 64, 2 * 4), 512, 0, stream>>>(qkv, vt);

    // 7) output projection: A=qkv cols 0..2047 (bf16, lda=3072, async DMA)
    gemm_bt<<<dim3(CE / 128, BT / 128), 256, 0, stream>>>(
        qkv, wqkvb, d_out, BT, CE, CE, NQKV, 0, 1, flagp);
}